// Round 1
// baseline (258.347 us; speedup 1.0000x reference)
//
#include <hip/hip_runtime.h>
#include <math.h>

// Problem constants
#define BB 8
#define NN 2048
#define FIN 256
#define FMSG 128
#define TOPK 32
#define NODES (BB * NN)   // 16384

// ---------------- Kernel 1: Xm = X @ W^T + b  (fp32, tiled) ----------------
// Tile: 32 nodes x 128 outputs, K-tiles of 32. Block 256 threads, grid 512.
#define NT 32
#define KT 32
#define PAD 36   // float4-aligned row stride, banks spread

__global__ __launch_bounds__(256) void linear_kernel(
    const float* __restrict__ X, const float* __restrict__ W,
    const float* __restrict__ bias, float* __restrict__ Xm) {
  __shared__ float sX[NT][PAD];
  __shared__ float sW[FMSG][PAD];
  const int tid = threadIdx.x;
  const int tm = tid & 15;    // m-group: m = tm + 16*j, j<8
  const int tn = tid >> 4;    // node-group: node = tn + 16*i, i<2
  const long long node_base = (long long)blockIdx.x * NT;

  float acc[2][8];
#pragma unroll
  for (int j = 0; j < 8; ++j) {
    float bj = bias[tm + 16 * j];
#pragma unroll
    for (int i = 0; i < 2; ++i) acc[i][j] = bj;
  }

  for (int kt = 0; kt < FIN; kt += KT) {
    __syncthreads();
    // stage X tile: 32 rows x 32 k = 256 float4, 1 per thread
    {
      int n = tid >> 3;
      int k4 = (tid & 7) << 2;
      float4 v = *reinterpret_cast<const float4*>(X + (node_base + n) * FIN + kt + k4);
      *reinterpret_cast<float4*>(&sX[n][k4]) = v;
    }
    // stage W tile: 128 rows x 32 k = 1024 float4, 4 per thread
#pragma unroll
    for (int q = 0; q < 4; ++q) {
      int f = tid + 256 * q;
      int m = f >> 3;
      int k4 = (f & 7) << 2;
      float4 v = *reinterpret_cast<const float4*>(W + m * FIN + kt + k4);
      *reinterpret_cast<float4*>(&sW[m][k4]) = v;
    }
    __syncthreads();
#pragma unroll
    for (int k = 0; k < KT; k += 4) {
      float4 xv[2], wv[8];
#pragma unroll
      for (int i = 0; i < 2; ++i)
        xv[i] = *reinterpret_cast<const float4*>(&sX[tn + 16 * i][k]);
#pragma unroll
      for (int j = 0; j < 8; ++j)
        wv[j] = *reinterpret_cast<const float4*>(&sW[tm + 16 * j][k]);
#pragma unroll
      for (int i = 0; i < 2; ++i)
#pragma unroll
        for (int j = 0; j < 8; ++j) {
          acc[i][j] += xv[i].x * wv[j].x;
          acc[i][j] += xv[i].y * wv[j].y;
          acc[i][j] += xv[i].z * wv[j].z;
          acc[i][j] += xv[i].w * wv[j].w;
        }
    }
  }
#pragma unroll
  for (int i = 0; i < 2; ++i)
#pragma unroll
    for (int j = 0; j < 8; ++j)
      Xm[(node_base + tn + 16 * i) * FMSG + tm + 16 * j] = acc[i][j];
}

// ------------- Kernel 2: fused top-K + BN/LeakyReLU weighted aggregate -------------
// One wave (64 lanes) per node; block = 4 waves; grid = NODES/4 = 4096.
// batch = blockIdx.x & 7 so consecutive blocks (round-robin over XCDs) keep one
// batch's Xm slice (1 MB) hot in that XCD's L2.
__global__ __launch_bounds__(256) void topk_agg_kernel(
    const float* __restrict__ A, const float* __restrict__ Xm,
    const float* __restrict__ gamma, const float* __restrict__ beta,
    const float* __restrict__ mean, const float* __restrict__ var,
    float* __restrict__ out) {
  __shared__ unsigned long long cand[4][64];

  const int lane = threadIdx.x & 63;
  const int w = threadIdx.x >> 6;
  const int batch = blockIdx.x & 7;
  const int n = ((blockIdx.x >> 3) << 2) + w;          // node within batch
  const long long row = (long long)batch * NN + n;

  // ---- load my 32 contiguous elements of the adjacency row ----
  const float* arow = A + row * NN;
  float a[32];
#pragma unroll
  for (int q = 0; q < 8; ++q) {
    float4 v = *reinterpret_cast<const float4*>(arow + lane * 32 + q * 4);
    a[q * 4 + 0] = v.x; a[q * 4 + 1] = v.y; a[q * 4 + 2] = v.z; a[q * 4 + 3] = v.w;
  }

  // ---- per-lane max ----
  float lmax = a[0];
#pragma unroll
  for (int r = 1; r < 32; ++r) lmax = fmaxf(lmax, a[r]);

  // ---- T = 32nd largest lane-max (descending bitonic sort of 64 lane maxima) ----
  float sv = lmax;
#pragma unroll
  for (int kk = 2; kk <= 64; kk <<= 1) {
#pragma unroll
    for (int jj = kk >> 1; jj > 0; jj >>= 1) {
      float o = __shfl_xor(sv, jj);
      bool takeMax = ((lane & kk) == 0) ^ ((lane & jj) != 0);
      sv = takeMax ? fmaxf(sv, o) : fminf(sv, o);
    }
  }
  const float T = __shfl(sv, 31);   // >=32 elements are >= T, guaranteed

  // ---- count candidates (elements >= T) and prefix-sum across lanes ----
  int cnt = 0;
#pragma unroll
  for (int r = 0; r < 32; ++r) cnt += (a[r] >= T) ? 1 : 0;
  int pre = cnt;
#pragma unroll
  for (int jj = 1; jj < 64; jj <<= 1) {
    int o = __shfl_up(pre, jj);
    if (lane >= jj) pre += o;
  }
  const int C = __shfl(pre, 63);
  int off = pre - cnt;   // exclusive prefix

  float selv = 0.0f;     // this lane's selected value (lanes 0..31 hold top-32 desc)
  int selj = 0;          // its column index

  if (C <= 64) {
    // ---- fast path: compact candidates to LDS, bitonic-sort 64b keys ----
    unsigned long long* cb = cand[w];
    cb[lane] = 0ULL;   // pad
    __builtin_amdgcn_wave_barrier();
#pragma unroll
    for (int r = 0; r < 32; ++r) {
      if (a[r] >= T) {
        unsigned fb = __float_as_uint(a[r]);
        // key: value desc, then index asc (complement index)
        unsigned long long kk = ((unsigned long long)fb << 32) |
                                (unsigned)(NN - 1 - (lane * 32 + r));
        cb[off] = kk;
        ++off;
      }
    }
    __builtin_amdgcn_wave_barrier();
    unsigned long long key = cb[lane];
#pragma unroll
    for (int kk = 2; kk <= 64; kk <<= 1) {
#pragma unroll
      for (int jj = kk >> 1; jj > 0; jj >>= 1) {
        unsigned long long o = __shfl_xor(key, jj);
        bool takeMax = ((lane & kk) == 0) ^ ((lane & jj) != 0);
        key = (takeMax == (key >= o)) ? key : o;
      }
    }
    if (lane < TOPK) {
      selv = __uint_as_float((unsigned)(key >> 32));
      selj = (NN - 1) - (int)(key & 0xFFFFFFFFull);
    }
  } else {
    // ---- rare exact fallback: iterative argmax with removal mask ----
    float bmax = a[0]; int bidx = 0;
#pragma unroll
    for (int r = 1; r < 32; ++r) {
      if (a[r] > bmax) { bmax = a[r]; bidx = r; }
    }
    unsigned rm = 0u;
    for (int t = 0; t < TOPK; ++t) {
      float bv = bmax; int bj = (lane << 5) | bidx;
#pragma unroll
      for (int s = 1; s < 64; s <<= 1) {
        float ov = __shfl_xor(bv, s);
        int oj = __shfl_xor(bj, s);
        if (ov > bv || (ov == bv && oj < bj)) { bv = ov; bj = oj; }
      }
      if (lane == t) { selv = bv; selj = bj; }
      if ((bj >> 5) == lane) {
        rm |= 1u << (bj & 31);
        bmax = -3.402823466e+38f; bidx = 0;
#pragma unroll
        for (int r = 0; r < 32; ++r) {
          float av = ((rm >> r) & 1u) ? -3.402823466e+38f : a[r];
          if (av > bmax) { bmax = av; bidx = r; }
        }
      }
    }
  }

  // ---- sum of selected values (lanes >= 32 contribute 0) ----
  float vs = selv;
#pragma unroll
  for (int jj = 1; jj < 64; jj <<= 1) vs += __shfl_xor(vs, jj);
  const float recip = 1.0f / (vs + 1e-12f);

  // ---- aggregation: each lane owns 2 channels ----
  const int c0 = lane * 2;
  const float2 gm = *reinterpret_cast<const float2*>(gamma + c0);
  const float2 bt = *reinterpret_cast<const float2*>(beta + c0);
  const float2 mn = *reinterpret_cast<const float2*>(mean + c0);
  const float2 vr = *reinterpret_cast<const float2*>(var + c0);
  const float is0 = 1.0f / sqrtf(vr.x + 1e-5f);
  const float is1 = 1.0f / sqrtf(vr.y + 1e-5f);
  const float sc0 = is0 * gm.x, sc1 = is1 * gm.y;
  const float sh0 = bt.x - mn.x * sc0, sh1 = bt.y - mn.y * sc1;

  const float* xmb = Xm + (long long)batch * NN * FMSG;
  const float2 xs = *reinterpret_cast<const float2*>(xmb + n * FMSG + c0);

  float acc0 = 0.0f, acc1 = 0.0f;
#pragma unroll
  for (int t = 0; t < TOPK; ++t) {
    float wgt = __shfl(selv, t) * recip;
    int j = __shfl(selj, t);
    float2 xn = *reinterpret_cast<const float2*>(xmb + j * FMSG + c0);
    float p0 = xs.x + xn.x;
    float p1 = xs.y + xn.y;
    float h0 = p0 * sc0 + sh0;
    float h1 = p1 * sc1 + sh1;
    h0 = fmaxf(h0, 0.01f * h0);   // LeakyReLU (slope 0.01), exact for both signs
    h1 = fmaxf(h1, 0.01f * h1);
    acc0 += wgt * h0;
    acc1 += wgt * h1;
  }
  *reinterpret_cast<float2*>(out + row * FMSG + c0) = make_float2(acc0, acc1);
}

// ---------------------------------------------------------------------------
extern "C" void kernel_launch(void* const* d_in, const int* in_sizes, int n_in,
                              void* d_out, int out_size, void* d_ws, size_t ws_size,
                              hipStream_t stream) {
  const float* X     = (const float*)d_in[0];
  const float* A     = (const float*)d_in[1];
  const float* W     = (const float*)d_in[2];
  const float* bias  = (const float*)d_in[3];
  const float* gamma = (const float*)d_in[4];
  const float* beta  = (const float*)d_in[5];
  const float* mean  = (const float*)d_in[6];
  const float* var   = (const float*)d_in[7];
  float* out = (float*)d_out;
  float* Xm  = (float*)d_ws;   // 16384 * 128 floats = 8 MB

  linear_kernel<<<NODES / NT, 256, 0, stream>>>(X, W, bias, Xm);
  topk_agg_kernel<<<NODES / 4, 256, 0, stream>>>(A, Xm, gamma, beta, mean, var, out);
}